// Round 12
// baseline (214.716 us; speedup 1.0000x reference)
//
#include <hip/hip_runtime.h>

// HybridQLSTMQuantum, MI355X — v12.
//   K1: 4 outputs/lane (wregQ[4][8] register-resident, launch_bounds(512,2));
//       each ds_read_b128 feeds 16 FMA (was 4) -> LDS-pipe pressure /4.
//       X staged via global_load_lds, double-buffered (vmcnt(4) interleave).
//   K2: 4-WAY gate split: 32 lanes per b-row (2 b/wave, 128 blocks); each
//       lane runs ONE gate pipeline. Exchange via row_ror:8 + ds_swizzle
//       xor16 + 8 cndmask (mapping verified per-gate by hand).
//
// qgate identity (verified analytically):
//   qgate(angles)[w] = prod_{j<=w} cos(angles[j])
//
// v6 single-kernel fallback retained for small ws.

#define S_LEN 256
#define BATCH 256
#define DIMK  256
#define FAN   264
#define NROWS (S_LEN * BATCH)
#define WS_NEED ((size_t)NROWS * 32 * 4)

typedef __attribute__((address_space(1))) const void GV;
typedef __attribute__((address_space(3))) void LV;

__device__ __forceinline__ float lo16f(unsigned u) {
    union { unsigned u; float f; } v; v.u = u << 16; return v.f;
}
__device__ __forceinline__ float hi16f(unsigned u) {
    union { unsigned u; float f; } v; v.u = u & 0xffff0000u; return v.f;
}
__device__ __forceinline__ float b2f(unsigned short u) {
    union { unsigned u; float f; } v; v.u = ((unsigned)u) << 16; return v.f;
}
__device__ __forceinline__ unsigned short f2b(float f) {
    union { float f; unsigned u; } v; v.f = f;
    unsigned r = v.u + 0x7fffu + ((v.u >> 16) & 1u);  // RNE
    return (unsigned short)(r >> 16);
}
__device__ __forceinline__ float sane(float x) {
    return (__builtin_fabsf(x) < 1e30f) ? x : 0.f;   // NaN compares false -> 0
}
__device__ __forceinline__ float ldE(const void* p, int idx, bool f32) {
    return f32 ? ((const float*)p)[idx] : b2f(((const unsigned short*)p)[idx]);
}
__device__ __forceinline__ void stE(void* p, long idx, float v, bool f32) {
    if (f32) ((float*)p)[idx] = v;
    else     ((unsigned short*)p)[idx] = f2b(v);
}
// Pade(5,4) tanh: err<=1e-4 for |x|<=2.2 (|c|<=~2.07 by gate bounds)
__device__ __forceinline__ float tanh_pade(float x) {
    float x2 = x * x;
    float num = x * fmaf(x2, x2 + 105.f, 945.f);
    float den = fmaf(x2, fmaf(x2, 15.f, 420.f), 945.f);
    return __fdividef(num, den);
}
__device__ __forceinline__ float tanh_f(float x) {   // exp-based (fallback kernel)
    return 1.f - __fdividef(2.f, __expf(2.f * x) + 1.f);
}
__device__ __forceinline__ float sigp(float x) {     // fallback helper
    float x2 = x * x;
    float p = fmaf(x2, 0.0026216f, -0.0217557f);
    p = fmaf(x2, p, 0.250193f);
    return fmaf(x, p, 0.5f);
}

// DPP: 0x00-0xFF quad_perm; 0x110|K row_shr:K; 0x120|K row_ror:K; 0x141 half_mirror.
template<int CTRL>
__device__ __forceinline__ float dpp_f(float x) {
    int xi = __builtin_bit_cast(int, x);
    int r = __builtin_amdgcn_update_dpp(xi, xi, CTRL, 0xF, 0xF, false);
    return __builtin_bit_cast(float, r);
}
template<int IMM>
__device__ __forceinline__ float swz_f(float x) {
    return __builtin_bit_cast(float,
        __builtin_amdgcn_ds_swizzle(__builtin_bit_cast(int, x), IMM));
}
__device__ __forceinline__ float rdlane_f(float x, int l) {
    return __builtin_bit_cast(float,
        __builtin_amdgcn_readlane(__builtin_bit_cast(int, x), l));
}

__device__ __forceinline__ int sniff_f32(const void* X) {
    const unsigned short* u = (const unsigned short*)X;
    int hits = 0;
    for (int i = 0; i < 64; ++i) {
        int e = (u[2 * i] >> 7) & 0xFF;
        if (e >= 110 && e <= 135) ++hits;
    }
    return (hits < 32) ? 1 : 0;
}

// ============================ K1: GEMM -> ws ============================
// 512 thr = 8 waves; wave kv owns k in [kv*32,kv*32+32). Lane l: output
// column o4 = l&7 for ALL 4 gates (wregQ[4][8] in VGPRs), row group
// rg8 = l>>3 (4 rows per chunk). Each ds_read_b128 feeds 16 FMA.
// X double-buffered in LDS via global_load_lds (vmcnt(4) interleave).
__global__ __launch_bounds__(512, 2) void qlstm_gemm(
    const void* __restrict__ X,
    const void* __restrict__ Wf, const void* __restrict__ Wi,
    const void* __restrict__ Wu, const void* __restrict__ Wo,
    const void* __restrict__ bf_, const void* __restrict__ bi_,
    const void* __restrict__ bu_, const void* __restrict__ bo_,
    const void* __restrict__ tf, const void* __restrict__ ti,
    const void* __restrict__ tu, const void* __restrict__ to_,
    float* __restrict__ A)
{
    __shared__ float Xs[2][8][32][32];   // 64 KiB: [chunkbuf][kv][row][k]
    __shared__ float red[8][32][32];     // 32 KiB k-partials

    const int tid = threadIdx.x;
    const bool f32 = sniff_f32(X) != 0;

    const int kv  = tid >> 6;        // wave = k-slice (0..7)
    const int l   = tid & 63;
    const int o4  = l & 7;           // output column (w); gates = 0..3
    const int rg8 = l >> 3;          // row group (0..7), 4 rows each
    const void* Wq[4] = { Wf, Wi, Wu, Wo };
    const void* bg_[4] = { bf_, bi_, bu_, bo_ };
    const void* tg_[4] = { tf, ti, tu, to_ };

    // W rows for wire o4, all 4 gates, k-slice kv: 128 VGPR (cap 256)
    float4 wregQ[4][8];
#pragma unroll
    for (int q = 0; q < 4; ++q) {
        if (f32) {
            const float4* wr = (const float4*)((const float*)Wq[q] + o4 * FAN + kv * 32);
#pragma unroll
            for (int i = 0; i < 8; ++i) wregQ[q][i] = wr[i];
        } else {
            const uint4* wr = (const uint4*)((const unsigned short*)Wq[q] + o4 * FAN + kv * 32);
#pragma unroll
            for (int i = 0; i < 4; ++i) {
                uint4 wu = wr[i];
                wregQ[q][2 * i + 0] = make_float4(lo16f(wu.x), hi16f(wu.x),
                                                  lo16f(wu.y), hi16f(wu.y));
                wregQ[q][2 * i + 1] = make_float4(lo16f(wu.z), hi16f(wu.z),
                                                  lo16f(wu.w), hi16f(wu.w));
            }
        }
    }

    const long rowbase = (long)blockIdx.x * 64;   // rows = b*256 + t

    auto stageX = [&](int chunk, int cbuf) {
#pragma unroll
        for (int i = 0; i < 4; ++i) {
            const long row = rowbase + chunk * 32 + i * 8 + (l >> 3);
            const int t = (int)(row & 255), bb = (int)(row >> 8);
            const float* src = (const float*)X
                    + ((long)t * BATCH + bb) * DIMK + kv * 32 + (l & 7) * 4;
            __builtin_amdgcn_global_load_lds((GV*)src,
                    (LV*)&Xs[cbuf][kv][i * 8][0], 16, 0, 0);
        }
    };
    auto computeChunk = [&](int cbuf) {
        for (int j = 0; j < 4; ++j) {
            const int r = rg8 * 4 + j;
            const float4* xv = (const float4*)&Xs[cbuf][kv][r][0];
            float4 x8[8];
#pragma unroll
            for (int i = 0; i < 8; ++i) x8[i] = xv[i];
#pragma unroll
            for (int q = 0; q < 4; ++q) {
                float a0 = 0.f, a1 = 0.f, a2 = 0.f, a3 = 0.f;
#pragma unroll
                for (int i = 0; i < 8; ++i) {
                    a0 = fmaf(x8[i].x, wregQ[q][i].x, a0);
                    a1 = fmaf(x8[i].y, wregQ[q][i].y, a1);
                    a2 = fmaf(x8[i].z, wregQ[q][i].z, a2);
                    a3 = fmaf(x8[i].w, wregQ[q][i].w, a3);
                }
                red[kv][r][q * 8 + o4] = (a0 + a1) + (a2 + a3);
            }
        }
    };
    auto reduceWrite = [&](int chunk) {
        for (int idx = tid; idx < 32 * 32; idx += 512) {
            const int rl = idx >> 5, oo = idx & 31;
            float s = 0.f;
#pragma unroll
            for (int k = 0; k < 8; ++k) s += red[k][rl][oo];
            const int g2 = oo >> 3, w2 = oo & 7;
            const float bt = sane(ldE(bg_[g2], w2, f32))
                           + sane(ldE(tg_[g2], w2, f32));
            A[(rowbase + chunk * 32 + rl) * 32 + w2 * 4 + g2] = sane(s) + bt;
        }
    };

    if (f32) {
        stageX(0, 0);
        stageX(1, 1);
        asm volatile("s_waitcnt vmcnt(4)" ::: "memory");  // chunk 0 resident
        computeChunk(0);
        __syncthreads();
        reduceWrite(0);
        __syncthreads();
        asm volatile("s_waitcnt vmcnt(0)" ::: "memory");  // chunk 1 resident
        computeChunk(1);
        __syncthreads();
        reduceWrite(1);
    } else {
        // bf16 fallback: direct global reads, same 4-output structure
        for (int chunk = 0; chunk < 2; ++chunk) {
            for (int j = 0; j < 4; ++j) {
                const int r = rg8 * 4 + j;
                const long row = rowbase + chunk * 32 + r;
                const int t = (int)(row & 255), bb = (int)(row >> 8);
                const uint4* xr = (const uint4*)((const unsigned short*)X
                        + ((long)t * BATCH + bb) * DIMK + kv * 32);
                uint4 xu[4];
#pragma unroll
                for (int i = 0; i < 4; ++i) xu[i] = xr[i];
                float4 x8[8];
#pragma unroll
                for (int i = 0; i < 4; ++i) {
                    x8[2 * i + 0] = make_float4(lo16f(xu[i].x), hi16f(xu[i].x),
                                                lo16f(xu[i].y), hi16f(xu[i].y));
                    x8[2 * i + 1] = make_float4(lo16f(xu[i].z), hi16f(xu[i].z),
                                                lo16f(xu[i].w), hi16f(xu[i].w));
                }
#pragma unroll
                for (int q = 0; q < 4; ++q) {
                    float a0 = 0.f, a1 = 0.f, a2 = 0.f, a3 = 0.f;
#pragma unroll
                    for (int i = 0; i < 8; ++i) {
                        a0 = fmaf(x8[i].x, wregQ[q][i].x, a0);
                        a1 = fmaf(x8[i].y, wregQ[q][i].y, a1);
                        a2 = fmaf(x8[i].z, wregQ[q][i].z, a2);
                        a3 = fmaf(x8[i].w, wregQ[q][i].w, a3);
                    }
                    red[kv][r][q * 8 + o4] = (a0 + a1) + (a2 + a3);
                }
            }
            __syncthreads();
            reduceWrite(chunk);
            __syncthreads();
        }
    }
}

// ========================= K2: recurrence (4-way gate split) =========================
// 128 blocks x 64 thr; wave = 2 b-rows x 32 lanes. Lane p = g(0..3) x w(0..7):
// ONE gate pipeline per lane. Exchange: row_ror:8 (xor8) + ds_swizzle xor16;
// select via 8 cndmask. A (bias pre-folded) staged via global_load_lds,
// 2x16KB double buffer (4 chunks of 64 t).
__global__ __launch_bounds__(64) void qlstm_rec(
    const void* __restrict__ X,  const void* __restrict__ hx, const void* __restrict__ cx,
    const void* __restrict__ Wf, const void* __restrict__ Wi,
    const void* __restrict__ Wu, const void* __restrict__ Wo,
    void* __restrict__ out, const float* __restrict__ A)
{
    __shared__ float4 Abuf[2][1024];   // 32 KiB: [buf][b2*512 + t_loc*8 + w]

    const int tid = threadIdx.x;
    const bool f32 = sniff_f32(X) != 0;

    const int p  = tid & 31;           // within-b lane
    const int g  = p >> 3;             // gate: 0=F 1=I 2=U 3=O
    const int w  = p & 7;              // wire
    const int b2 = tid >> 5;           // 0..1
    const int bglob = blockIdx.x * 2 + b2;
    const bool gb0 = (g & 1) != 0, gb1 = (g & 2) != 0;

    const void* Wg = (g == 0) ? Wf : (g == 1) ? Wi : (g == 2) ? Wu : Wo;

    // XOR-permuted h-coefficients for this lane's gate only
    float Whm[8];
#pragma unroll
    for (int m = 0; m < 8; ++m)
        Whm[m] = sane(ldE(Wg, w * FAN + DIMK + (w ^ m), f32));

    // unified nonlinearity coeffs: g==2 (U) -> tanh, else sigmoid (err<=2e-4)
    const float d3 = (g == 2) ? -0.028402f : 0.f;
    const float d2 = (g == 2) ?  0.121713f : 0.0026216f;
    const float d1 = (g == 2) ? -0.331717f : -0.0217557f;
    const float d0 = (g == 2) ?  1.0f      : 0.250193f;
    const float s0 = (g == 2) ?  0.f       : 0.5f;

    float h = sane(ldE(hx, bglob * 8 + w, f32));
    float c = sane(ldE(cx, bglob * 8 + w, f32));

    auto cumprod8 = [&](float e) {
        { float v = dpp_f<0x111>(e); e = (w >= 1) ? e * v : e; }
        { float v = dpp_f<0x112>(e); e = (w >= 2) ? e * v : e; }
        { float v = dpp_f<0x114>(e); e = (w >= 4) ? e * v : e; }
        return e;
    };

    // staging: chunk = 64 t x 2 b = 1024 float4 = 16 issues x 64 lanes x 16B.
    // flat slot = i*64 + lane; b2 = flat>>9 -> issues 0-7 b0, 8-15 b1.
    // src float4 = blockbase + ch*512 + i*64 + lane + (i>=8 ? 1536 : 0).
    const float4* A4 = (const float4*)A;
    const float4* srcbase = A4 + (long)blockIdx.x * 4096;
    auto stage = [&](int ch, int bufi) {
#pragma unroll
        for (int i = 0; i < 16; ++i) {
            const float4* s = srcbase + ch * 512 + i * 64 + tid + (i >= 8 ? 1536 : 0);
            __builtin_amdgcn_global_load_lds((GV*)s,
                    (LV*)&Abuf[bufi][i * 64], 16, 0, 0);
        }
    };

    auto STEP = [&](int t, float a) {
        // h all-to-all within the 8-lane w-group via XOR-basis DPP
        float h0 = h;
        float h1 = dpp_f<0xB1>(h);
        float h2 = dpp_f<0x4E>(h);
        float h3 = dpp_f<0xB1>(h2);       // xor3
        float h7 = dpp_f<0x141>(h);
        float h6 = dpp_f<0xB1>(h7);       // xor6
        float h5 = dpp_f<0x4E>(h7);       // xor5
        float h4 = dpp_f<0xB1>(h5);       // xor4

        float da = fmaf(h0, Whm[0], a), db = h1 * Whm[1];
        da = fmaf(h2, Whm[2], da); db = fmaf(h3, Whm[3], db);
        da = fmaf(h4, Whm[4], da); db = fmaf(h5, Whm[5], db);
        da = fmaf(h6, Whm[6], da); db = fmaf(h7, Whm[7], db);
        float ang = da + db;

        float E = cumprod8(__cosf(ang));
        float x2 = E * E;
        float pp = fmaf(x2, d3, d2);
        pp = fmaf(x2, pp, d1);
        pp = fmaf(x2, pp, d0);
        float v = fmaf(E, pp, s0);        // this lane's gate value

        // gather the 4 gates of wire w: v8=g^1, v16=g^2, v24=g^3
        float v8  = dpp_f<0x128>(v);          // row_ror:8 = lane^8
        float v16 = swz_f<0x401F>(v);         // xor16 (32-lane domain)
        float v24 = swz_f<0x401F>(v8);
        float fa = gb0 ? v8  : v;
        float fb = gb0 ? v24 : v16;
        float ia = gb0 ? v   : v8;
        float ib = gb0 ? v16 : v24;
        float gf = gb1 ? fb : fa;             // gate 0 (F)
        float gu = gb1 ? fa : fb;             // gate 2 (U)
        float gi = gb1 ? ib : ia;             // gate 1 (I)
        float go = gb1 ? ia : ib;             // gate 3 (O)

        c = fmaf(gf, c, gi * gu);
        h = go * tanh_pade(c);                // all 32 lanes hold h_w
        if (g == 0)
            stE(out, (long)t * 2048 + bglob * 8 + w, h, f32);
    };

    stage(0, 0);
    asm volatile("s_waitcnt vmcnt(0)" ::: "memory");

    const float* Afl = (const float*)&Abuf[0][0];
    const int rdoff = b2 * 2048 + w * 4 + g;   // float index within buf
    for (int ch = 0; ch < 4; ++ch) {
        const int cb = ch & 1;
        if (ch + 1 < 4) stage(ch + 1, cb ^ 1);   // in flight across steps
#pragma unroll 4
        for (int s = 0; s < 64; ++s) {
            float a = Afl[cb * 4096 + s * 32 + rdoff];
            STEP(ch * 64 + s, a);
        }
        asm volatile("s_waitcnt vmcnt(0)" ::: "memory");   // next buf ready
    }
    if (g == 0) {
        stE(out, 524288L + bglob * 8 + w, h, f32);   // hT
        stE(out, 526336L + bglob * 8 + w, c, f32);   // cT
    }
}

// ================= v6 fallback (ws too small): proven at 140us =================
__global__ __launch_bounds__(320, 1) void qlstm_fused_v6(
    const void* __restrict__ X,  const void* __restrict__ hx, const void* __restrict__ cx,
    const void* __restrict__ Wf, const void* __restrict__ bf_,
    const void* __restrict__ Wi, const void* __restrict__ bi_,
    const void* __restrict__ Wu, const void* __restrict__ bu_,
    const void* __restrict__ Wo, const void* __restrict__ bo_,
    const void* __restrict__ tf, const void* __restrict__ ti,
    const void* __restrict__ tu, const void* __restrict__ to_,
    void* __restrict__ out)
{
    __shared__ float As4[2][4][32][32];

    const int tid = threadIdx.x;
    const int b   = blockIdx.x;
    const bool f32 = sniff_f32(X) != 0;

    const int wv   = tid >> 6;
    const int lane = tid & 63;
    const int kv   = wv - 1;
    const int o    = lane & 31;
    const int th   = lane >> 5;
    const int g    = o >> 3, w = o & 7;
    const void* Wg = (g == 0) ? Wf : (g == 1) ? Wi : (g == 2) ? Wu : Wo;

    float4 wreg[16];
    if (wv >= 1) {
        if (f32) {
            const float4* wr = (const float4*)((const float*)Wg + w * FAN + kv * 64);
#pragma unroll
            for (int i = 0; i < 16; ++i) wreg[i] = wr[i];
        } else {
            const uint4* wr = (const uint4*)((const unsigned short*)Wg + w * FAN + kv * 64);
#pragma unroll
            for (int i = 0; i < 8; ++i) {
                uint4 wu = wr[i];
                wreg[2 * i + 0] = make_float4(lo16f(wu.x), hi16f(wu.x),
                                              lo16f(wu.y), hi16f(wu.y));
                wreg[2 * i + 1] = make_float4(lo16f(wu.z), hi16f(wu.z),
                                              lo16f(wu.w), hi16f(wu.w));
            }
        }
    }

    auto fill = [&](int ch) {
        float (*dst)[32] = As4[ch & 1][kv];
        const int tb = ch * 32 + th * 16;
        if (f32) {
            for (int j = 0; j < 16; ++j) {
                const float4* xr = (const float4*)((const float*)X
                        + ((long)(tb + j) * BATCH + b) * DIMK + kv * 64);
                float a0 = 0.f, a1 = 0.f, a2 = 0.f, a3 = 0.f;
#pragma unroll
                for (int i = 0; i < 16; ++i) {
                    float4 xu = xr[i];
                    a0 = fmaf(xu.x, wreg[i].x, a0);
                    a1 = fmaf(xu.y, wreg[i].y, a1);
                    a2 = fmaf(xu.z, wreg[i].z, a2);
                    a3 = fmaf(xu.w, wreg[i].w, a3);
                }
                dst[th * 16 + j][o] = sane((a0 + a1) + (a2 + a3));
            }
        } else {
            for (int j = 0; j < 16; ++j) {
                const uint4* xr = (const uint4*)((const unsigned short*)X
                        + ((long)(tb + j) * BATCH + b) * DIMK + kv * 64);
                float a0 = 0.f, a1 = 0.f, a2 = 0.f, a3 = 0.f;
#pragma unroll
                for (int i = 0; i < 8; ++i) {
                    uint4 xu = xr[i];
                    a0 = fmaf(lo16f(xu.x), wreg[2 * i].x, a0);
                    a1 = fmaf(hi16f(xu.x), wreg[2 * i].y, a1);
                    a2 = fmaf(lo16f(xu.y), wreg[2 * i].z, a2);
                    a3 = fmaf(hi16f(xu.y), wreg[2 * i].w, a3);
                    a0 = fmaf(lo16f(xu.z), wreg[2 * i + 1].x, a0);
                    a1 = fmaf(hi16f(xu.z), wreg[2 * i + 1].y, a1);
                    a2 = fmaf(lo16f(xu.w), wreg[2 * i + 1].z, a2);
                    a3 = fmaf(hi16f(xu.w), wreg[2 * i + 1].w, a3);
                }
                dst[th * 16 + j][o] = sane((a0 + a1) + (a2 + a3));
            }
        }
    };

    float Wh[8];
    float bt = 0.f, h = 0.f, c = 0.f, qv = 1.f;
    int rw = 0, rg = 0;
    if (tid < 32) {
        rw = tid & 7; rg = tid >> 3;
        const void* bg = (rg == 0) ? bf_ : (rg == 1) ? bi_ : (rg == 2) ? bu_ : bo_;
        const void* tg = (rg == 0) ? tf  : (rg == 1) ? ti  : (rg == 2) ? tu  : to_;
        const int wr = rw * FAN;
#pragma unroll
        for (int j = 0; j < 8; ++j)
            Wh[j] = sane(ldE(Wg, wr + DIMK + j, f32));
        bt = sane(ldE(bg, rw, f32)) + sane(ldE(tg, rw, f32));
        h  = sane(ldE(hx, b * 8 + rw, f32));
        c  = sane(ldE(cx, b * 8 + rw, f32));
        qv = (rg == 2) ? 2.f : 1.f;
    }
    if (wv == 0) __builtin_amdgcn_s_setprio(1);

    if (wv >= 1) fill(0);
    __syncthreads();

    for (int ch = 0; ch < 8; ++ch) {
        if (wv >= 1 && ch + 1 < 8) fill(ch + 1);
        if (tid < 32) {
            const int buf = ch & 1;
            float n0 = As4[buf][0][0][tid], n1 = As4[buf][1][0][tid];
            float n2 = As4[buf][2][0][tid], n3 = As4[buf][3][0][tid];
            float a_cur = (n0 + n1) + (n2 + n3);
            for (int s = 0; s < 32; ++s) {
                const int sn = (s < 31) ? s + 1 : s;
                float m0 = As4[buf][0][sn][tid], m1 = As4[buf][1][sn][tid];
                float m2 = As4[buf][2][sn][tid], m3 = As4[buf][3][sn][tid];
                float dd0 = 0.f, dd1 = 0.f;
#pragma unroll
                for (int j = 0; j < 8; j += 2) {
                    dd0 = fmaf(rdlane_f(h, j),     Wh[j],     dd0);
                    dd1 = fmaf(rdlane_f(h, j + 1), Wh[j + 1], dd1);
                }
                float ang = a_cur + bt + (dd0 + dd1);
                float e = __cosf(ang);
                { float v = dpp_f<0x111>(e); e = (rw >= 1) ? e * v : e; }
                { float v = dpp_f<0x112>(e); e = (rw >= 2) ? e * v : e; }
                { float v = dpp_f<0x114>(e); e = (rw >= 4) ? e * v : e; }
                float ez  = __expf(qv * e);
                float val = 1.f - __fdividef(qv, ez + 1.f);
                float fg = swz_f<0x007>(val);
                float ig = swz_f<0x107>(val);
                float ug = swz_f<0x207>(val);
                float og = swz_f<0x307>(val);
                c = fmaf(fg, c, ig * ug);
                float e2 = __expf(2.f * c);
                float th2 = 1.f - __fdividef(2.f, e2 + 1.f);
                h = og * th2;
                if (rg == 0)
                    stE(out, (long)(ch * 32 + s) * 2048 + b * 8 + rw, h, f32);
                a_cur = (m0 + m1) + (m2 + m3);
            }
        }
        __syncthreads();
    }

    if (tid < 32 && rg == 0) {
        stE(out, 524288L + b * 8 + rw, h, f32);
        stE(out, 526336L + b * 8 + rw, c, f32);
    }
}

extern "C" void kernel_launch(void* const* d_in, const int* in_sizes, int n_in,
                              void* d_out, int out_size, void* d_ws, size_t ws_size,
                              hipStream_t stream) {
    if (d_ws != nullptr && ws_size >= WS_NEED) {
        qlstm_gemm<<<dim3(NROWS / 64), dim3(512), 0, stream>>>(
            d_in[0], d_in[3], d_in[5], d_in[7], d_in[9],
            d_in[4], d_in[6], d_in[8], d_in[10],
            d_in[11], d_in[12], d_in[13], d_in[14],
            (float*)d_ws);
        qlstm_rec<<<dim3(BATCH / 2), dim3(64), 0, stream>>>(
            d_in[0], d_in[1], d_in[2],
            d_in[3], d_in[5], d_in[7], d_in[9],
            d_out, (const float*)d_ws);
    } else {
        qlstm_fused_v6<<<dim3(BATCH), dim3(320), 0, stream>>>(
            d_in[0], d_in[1], d_in[2],
            d_in[3], d_in[4], d_in[5], d_in[6],
            d_in[7], d_in[8], d_in[9], d_in[10],
            d_in[11], d_in[12], d_in[13], d_in[14],
            d_out);
    }
}